// Round 2
// baseline (59.982 us; speedup 1.0000x reference)
//
#include <hip/hip_runtime.h>

#define GSZ   64
#define G3    (GSZ * GSZ * GSZ)      // 262144
#define NCAM  8
#define NJ    23
#define IMW   1280
#define IMH   1024
#define HMW   (IMW / 2)              // 640
#define HMH   (IMH / 2)              // 512
#define HWSZ  (HMW * HMH)            // 327680

__global__ __launch_bounds__(256) void reproj_kernel(
    const float* __restrict__ hm,      // [B, C, J, 512, 640]
    const float* __restrict__ center,  // [B, 3]
    const float* __restrict__ cam,     // [B, C, 4, 3]
    float* __restrict__ out)           // [B, J, 64, 64, 64]
{
#pragma clang fp contract(off)
    const int b = blockIdx.y;
    const int n = blockIdx.x * blockDim.x + threadIdx.x;   // 0 .. G3-1
    const int z = n & 63;
    const int y = (n >> 6) & 63;
    const int x = n >> 12;

    // stage this batch's 8 camera matrices (96 floats) in LDS
    __shared__ float sM[NCAM * 12];
    if (threadIdx.x < NCAM * 12) {
        sM[threadIdx.x] = cam[b * NCAM * 12 + threadIdx.x];
    }
    __syncthreads();

    const float cx = center[b * 3 + 0];
    const float cy = center[b * 3 + 1];
    const float cz = center[b * 3 + 2];
    // grid value: (coord - 32) * 2 + center; the *2 product is exact so
    // mul+add == fma here — no ambiguity vs reference.
    const float px = (float)(x - 32) * 2.0f + cx;
    const float py = (float)(y - 32) * 2.0f + cy;
    const float pz = (float)(z - 32) * 2.0f + cz;

    float acc[NJ];
#pragma unroll
    for (int j = 0; j < NJ; ++j) acc[j] = 0.0f;

    const float* hmb = hm + (size_t)b * NCAM * NJ * HWSZ;

    for (int c = 0; c < NCAM; ++c) {
        const float* M = &sM[c * 12];   // M[k*3 + m]
        // XLA/Eigen gemm ordering: sequential FMA along ascending k.
        // fma(h0,m0,0) == h0*m0 (single rounding); tail +M[9] == fma(1,M9,·).
        float p0 = fmaf(pz, M[6], fmaf(py, M[3], px * M[0])) + M[9];
        float p1 = fmaf(pz, M[7], fmaf(py, M[4], px * M[1])) + M[10];
        float p2 = fmaf(pz, M[8], fmaf(py, M[5], px * M[2])) + M[11];

        float u = p0 / p2;              // IEEE divide (no fast-math)
        float v = p1 / p2;
        u = fminf(fmaxf(u, 0.0f), (float)(IMW - 1));
        v = fminf(fmaxf(v, 0.0f), (float)(IMH - 1));
        const int idx = (int)(v * 0.5f) * HMW + (int)(u * 0.5f);

        const float* plane = hmb + (size_t)c * NJ * HWSZ + idx;
#pragma unroll
        for (int j = 0; j < NJ; ++j) {
            acc[j] += plane[(size_t)j * HWSZ];
        }
    }

    float* ob = out + (size_t)b * NJ * G3 + n;
#pragma unroll
    for (int j = 0; j < NJ; ++j) {
        ob[(size_t)j * G3] = acc[j] * 0.125f;
    }
}

extern "C" void kernel_launch(void* const* d_in, const int* in_sizes, int n_in,
                              void* d_out, int out_size, void* d_ws, size_t ws_size,
                              hipStream_t stream) {
    const float* hm     = (const float*)d_in[0];
    const float* center = (const float*)d_in[1];
    const float* cam    = (const float*)d_in[2];
    float* out          = (float*)d_out;

    dim3 grid(G3 / 256, 2, 1);
    dim3 block(256, 1, 1);
    reproj_kernel<<<grid, block, 0, stream>>>(hm, center, cam, out);
}